// Round 7
// baseline (309.906 us; speedup 1.0000x reference)
//
#include <hip/hip_runtime.h>
#include <hip/hip_bf16.h>

#define LOG2E 1.4426950408889634f

typedef __attribute__((ext_vector_type(4)))  float f32x4;
typedef __attribute__((ext_vector_type(16))) float f32x16;
typedef __attribute__((ext_vector_type(8)))  short s16x8;
typedef __attribute__((ext_vector_type(8)))  unsigned short u16x8_t;
typedef __attribute__((ext_vector_type(4)))  int i32x4;

static __device__ __forceinline__ unsigned short f2b(float f) {
    __hip_bfloat16 h = __float2bfloat16(f);
    return __builtin_bit_cast(unsigned short, h);
}

// async global->LDS, 16 bytes per lane (dest must be linear: base + lane*16)
static __device__ __forceinline__ void gload_lds16(const unsigned short* g, unsigned short* l) {
    __builtin_amdgcn_global_load_lds(
        (const __attribute__((address_space(1))) void*)g,
        (__attribute__((address_space(3))) void*)l, 16, 0, 0);
}

// ---------------------------------------------------------------------------
// f32 -> bf16 vectorized x4
// ---------------------------------------------------------------------------
__global__ void cvt_f32_to_bf16(const float* __restrict__ src,
                                unsigned short* __restrict__ dst, int n4) {
    int i = blockIdx.x * blockDim.x + threadIdx.x;
    int stride = gridDim.x * blockDim.x;
    for (; i < n4; i += stride) {
        f32x4 v = reinterpret_cast<const f32x4*>(src)[i];
        ushort4 o;
        o.x = f2b(v.x); o.y = f2b(v.y); o.z = f2b(v.z); o.w = f2b(v.w);
        reinterpret_cast<ushort4*>(dst)[i] = o;
    }
}

// All 4 weight matrices -> one concatenated bf16 buffer [3072][768]
__global__ void cvt_weights(const float* __restrict__ wq, const float* __restrict__ wk,
                            const float* __restrict__ wv, const float* __restrict__ wo,
                            unsigned short* __restrict__ dst, int quarter4) {
    int i = blockIdx.x * blockDim.x + threadIdx.x;  // in float4 units
    int seg = i / quarter4;
    int j = i - seg * quarter4;
    const float* src = (seg == 0) ? wq : (seg == 1) ? wk : (seg == 2) ? wv : wo;
    f32x4 v = reinterpret_cast<const f32x4*>(src)[j];
    ushort4 o;
    o.x = f2b(v.x); o.y = f2b(v.y); o.z = f2b(v.z); o.w = f2b(v.w);
    reinterpret_cast<ushort4*>(dst)[i] = o;
}

// ---------------------------------------------------------------------------
// Merged NT GEMM v2: double-buffered LDS + global_load_lds prefetch pipeline,
// XCD-chunked block swizzle (same-A blocks land on one XCD's L2).
// C[m][n] = A_seg[m][:] . Wcat[n][:], N = 3072 in 4 segments of 768:
// Q (bf16, *qscale) | K (bf16) | V (bf16, transposed per-head) | O (f32 adj).
// A = v1 for Q/O, v2 for K/V. 128x128 tile, 4 waves, BK=64, 12 k-steps.
// Per iter: STAGE(next tile) -> ds_read+MFMA(cur) -> __syncthreads (drains
// the just-issued DMA AFTER ~400cyc of compute cover).
// ---------------------------------------------------------------------------
__global__ __launch_bounds__(256) void gemm_qkvo(
    const unsigned short* __restrict__ A1,
    const unsigned short* __restrict__ A2,
    const unsigned short* __restrict__ Wcat,
    const float* __restrict__ bq, const float* __restrict__ bk,
    const float* __restrict__ bv, const float* __restrict__ bo,
    unsigned short* __restrict__ Qb,
    unsigned short* __restrict__ Kb,
    unsigned short* __restrict__ Vtb,
    float* __restrict__ adj,
    float qscale)
{
    __shared__ unsigned short As[2][128 * 64];
    __shared__ unsigned short Bs[2][128 * 64];

    // XCD-chunked swizzle: nwg=1536, 1536%8==0 -> bijective.
    const int bid = blockIdx.x;
    const int wg = (bid & 7) * 192 + (bid >> 3);
    const int mblk = wg / 24;          // 0..63  (8 contiguous m per XCD)
    const int nblk = wg - mblk * 24;   // 0..23
    const int n0g = nblk * 128;
    const int seg = nblk / 6;
    const int n0 = n0g - seg * 768;
    const int m0 = mblk * 128;
    const unsigned short* A = (seg == 1 || seg == 2) ? A2 : A1;
    const float* bias = (seg == 0) ? bq : (seg == 1) ? bk : (seg == 2) ? bv : bo;

    const int tid = threadIdx.x;
    const int w = tid >> 6, lane = tid & 63;
    const int lg = lane >> 4, lr = lane & 15;
    const int wm = w >> 1, wn = w & 1;
    const int srow = tid >> 3;          // 0..31
    const int scol = (tid & 7) * 8;     // elem

    const unsigned short* Ag = A    + (size_t)(m0  + srow) * 768 + scol;
    const unsigned short* Bg = Wcat + (size_t)(n0g + srow) * 768 + scol;

    auto STAGE = [&](int buf, int k0) {
#pragma unroll
        for (int c = 0; c < 4; c++) {
            gload_lds16(Ag + c * 32 * 768 + k0, &As[buf][tid * 8 + c * 2048]);
            gload_lds16(Bg + c * 32 * 768 + k0, &Bs[buf][tid * 8 + c * 2048]);
        }
    };

    f32x4 acc[4][4];
#pragma unroll
    for (int i = 0; i < 4; i++)
#pragma unroll
        for (int j = 0; j < 4; j++) acc[i][j] = f32x4{0.f, 0.f, 0.f, 0.f};

    STAGE(0, 0);
    __syncthreads();

#pragma unroll 1
    for (int t = 0; t < 12; t++) {
        const int curb = t & 1;
        if (t + 1 < 12) STAGE(curb ^ 1, (t + 1) * 64);   // prefetch next tile
#pragma unroll
        for (int kk = 0; kk < 2; ++kk) {
            s16x8 af[4], bf[4];
#pragma unroll
            for (int mi = 0; mi < 4; mi++)
                af[mi] = *reinterpret_cast<const s16x8*>(&As[curb][(wm * 64 + mi * 16 + lr) * 64 + kk * 32 + lg * 8]);
#pragma unroll
            for (int ni = 0; ni < 4; ni++)
                bf[ni] = *reinterpret_cast<const s16x8*>(&Bs[curb][(wn * 64 + ni * 16 + lr) * 64 + kk * 32 + lg * 8]);
#pragma unroll
            for (int mi = 0; mi < 4; mi++)
#pragma unroll
                for (int ni = 0; ni < 4; ni++)
                    acc[mi][ni] = __builtin_amdgcn_mfma_f32_16x16x32_bf16(af[mi], bf[ni], acc[mi][ni], 0, 0, 0);
        }
        __syncthreads();   // drains the prefetch DMA (covered by the compute above)
    }

#pragma unroll
    for (int ni = 0; ni < 4; ni++) {
        int n = n0 + wn * 64 + ni * 16 + lr;
        float bn = bias[n];
#pragma unroll
        for (int mi = 0; mi < 4; mi++) {
#pragma unroll
            for (int i = 0; i < 4; i++) {
                int m = m0 + wm * 64 + mi * 16 + 4 * lg + i;
                float v = acc[mi][ni][i] + bn;
                if (seg == 0) {
                    Qb[(size_t)m * 768 + n] = f2b(v * qscale);
                } else if (seg == 1) {
                    Kb[(size_t)m * 768 + n] = f2b(v);
                } else if (seg == 2) {
                    int bb = m >> 11, ss = m & 2047;
                    Vtb[((size_t)(bb * 768 + n) << 11) + ss] = f2b(v);
                } else {
                    adj[(size_t)m * 768 + n] = v;
                }
            }
        }
    }
}

// ---------------------------------------------------------------------------
// Fused flash attention v5. 32x32x16 MFMA, q lane-local throughout.
// Block: 128 threads (2 waves), wave owns 64 q rows (2 q-frags sharing every
// K/V fragment -> LDS read traffic per q HALVES vs v4). q-tile 128/block.
// Grid: (48 bh, 16 qblk). KT=64 k-tile, double-buffered LDS, 1 barrier/tile.
//
// No running max (logits bounded; softmax shift-invariant); LOG2E folded
// into Q prescale at the GEMM store -> p = exp2(sc) directly.
// Reg-staged pipeline: tile t+1 regs -> LDS while computing t; tile t+2
// global loads issued before compute.
//
// Swapped QK^T: S^T[k][q] = mfma(K, Q^T); C col = lane&31 = q,
//   row = (r&3)+8*(r>>2)+4*hi = k.  Swapped PV: out^T = mfma(V^T, P^T).
// P^T frags in-register via v_cvt_pk_bf16_f32 + v_permlane32_swap_b32.
// ---------------------------------------------------------------------------
__global__ __launch_bounds__(128, 2) void attn_fused(
    const unsigned short* __restrict__ Qb,
    const unsigned short* __restrict__ Kb,
    const unsigned short* __restrict__ Vt,
    const float* __restrict__ adj,
    const float* __restrict__ alpha_p,
    const float* __restrict__ beta_p,
    float* __restrict__ out)
{
    __shared__ unsigned short Ksm[2][64][72];   // [buf][k][d]
    __shared__ unsigned short Vsm[2][64][72];   // [buf][d][k]

    const int bh = blockIdx.x;
    const int b = bh / 12, h = bh - 12 * (bh / 12);
    const int tid = threadIdx.x, w = tid >> 6, lane = tid & 63;
    const int ql = lane & 31, hi = lane >> 5;
    const int q0 = blockIdx.y * 128 + w * 64;

    // Q fragments: 2 q-frags of 32 rows each
    const size_t qbase = ((size_t)(b * 2048 + q0 + ql)) * 768 + h * 64;
    s16x8 qreg[2][4];
#pragma unroll
    for (int qf = 0; qf < 2; qf++)
#pragma unroll
        for (int ds = 0; ds < 4; ds++)
            qreg[qf][ds] = *reinterpret_cast<const s16x8*>(Qb + qbase + (size_t)qf * 32 * 768 + ds * 16 + hi * 8);

    f32x16 z16;
#pragma unroll
    for (int r = 0; r < 16; r++) z16[r] = 0.f;
    f32x16 acc[2][2];   // [qf][dd]
#pragma unroll
    for (int qf = 0; qf < 2; qf++)
#pragma unroll
        for (int dd = 0; dd < 2; dd++) acc[qf][dd] = z16;
    float l0 = 0.f, l1 = 0.f;

    const size_t kbase = (size_t)b * 2048 * 768 + (size_t)h * 64;
    const size_t vbase = (size_t)(b * 768 + h * 64) * 2048;

    // staging: 128 threads, 64x64 tiles: 4 chunks of 16 rows each
    const int krow = tid >> 3, kc8 = (tid & 7) * 8;

    u16x8_t kst[4], vst[4];
    auto load_tile = [&](int t0) {
#pragma unroll
        for (int i = 0; i < 4; i++)
            kst[i] = *reinterpret_cast<const u16x8_t*>(Kb + kbase + (size_t)(t0 + i * 16 + krow) * 768 + kc8);
#pragma unroll
        for (int i = 0; i < 4; i++)
            vst[i] = *reinterpret_cast<const u16x8_t*>(Vt + vbase + (size_t)(i * 16 + krow) * 2048 + t0 + kc8);
    };
    auto write_tile = [&](int buf) {
#pragma unroll
        for (int i = 0; i < 4; i++)
            *reinterpret_cast<u16x8_t*>(&Ksm[buf][i * 16 + krow][kc8]) = kst[i];
#pragma unroll
        for (int i = 0; i < 4; i++)
            *reinterpret_cast<u16x8_t*>(&Vsm[buf][i * 16 + krow][kc8]) = vst[i];
    };

    load_tile(0);
    write_tile(0);
    load_tile(64);
    __syncthreads();

#pragma unroll 1
    for (int t = 0; t < 32; t++) {
        const int cur = t & 1;
        if (t + 1 < 32) write_tile(cur ^ 1);       // tile t+1 regs -> other buffer
        if (t + 2 < 32) load_tile((t + 2) * 64);   // issue next-next tile loads

#pragma unroll
        for (int kb2 = 0; kb2 < 2; kb2++) {
            // K fragments for this 32k slab (shared by both q-frags)
            s16x8 ka0 = *reinterpret_cast<const s16x8*>(&Ksm[cur][kb2 * 32 + ql][0 * 16 + hi * 8]);
            s16x8 ka1 = *reinterpret_cast<const s16x8*>(&Ksm[cur][kb2 * 32 + ql][1 * 16 + hi * 8]);
            s16x8 ka2 = *reinterpret_cast<const s16x8*>(&Ksm[cur][kb2 * 32 + ql][2 * 16 + hi * 8]);
            s16x8 ka3 = *reinterpret_cast<const s16x8*>(&Ksm[cur][kb2 * 32 + ql][3 * 16 + hi * 8]);
            // V fragments for this slab (shared by both q-frags)
            s16x8 va00 = *reinterpret_cast<const s16x8*>(&Vsm[cur][0 * 32 + ql][kb2 * 32 + 0 * 16 + hi * 8]);
            s16x8 va01 = *reinterpret_cast<const s16x8*>(&Vsm[cur][1 * 32 + ql][kb2 * 32 + 0 * 16 + hi * 8]);
            s16x8 va10 = *reinterpret_cast<const s16x8*>(&Vsm[cur][0 * 32 + ql][kb2 * 32 + 1 * 16 + hi * 8]);
            s16x8 va11 = *reinterpret_cast<const s16x8*>(&Vsm[cur][1 * 32 + ql][kb2 * 32 + 1 * 16 + hi * 8]);

#pragma unroll
            for (int qf = 0; qf < 2; qf++) {
                // --- QK^T ---
                __builtin_amdgcn_s_setprio(1);
                f32x16 sc = __builtin_amdgcn_mfma_f32_32x32x16_bf16(ka0, qreg[qf][0], z16, 0, 0, 0);
                sc = __builtin_amdgcn_mfma_f32_32x32x16_bf16(ka1, qreg[qf][1], sc, 0, 0, 0);
                sc = __builtin_amdgcn_mfma_f32_32x32x16_bf16(ka2, qreg[qf][2], sc, 0, 0, 0);
                sc = __builtin_amdgcn_mfma_f32_32x32x16_bf16(ka3, qreg[qf][3], sc, 0, 0, 0);
                __builtin_amdgcn_s_setprio(0);

                // --- p = exp2(sc) (LOG2E pre-folded into Q), tree-sum ---
                float p[16];
#pragma unroll
                for (int r = 0; r < 16; r++) p[r] = __builtin_exp2f(sc[r]);
                {
                    float s0 = p[0] + p[1],  s1 = p[2] + p[3],  s2 = p[4] + p[5],  s3 = p[6] + p[7];
                    float s4 = p[8] + p[9],  s5 = p[10] + p[11], s6 = p[12] + p[13], s7 = p[14] + p[15];
                    float t0a = s0 + s1, t1a = s2 + s3, t2a = s4 + s5, t3a = s6 + s7;
                    float ls = (t0a + t1a) + (t2a + t3a);
                    if (qf) l1 += ls; else l0 += ls;
                }

                // --- pack P^T fragments in-register ---
                s16x8 pf0, pf1;
                {
                    unsigned int a0, b0, a1, b1, a2, b2, a3, b3;
                    asm("v_cvt_pk_bf16_f32 %0, %1, %2" : "=v"(a0) : "v"(p[0]),  "v"(p[1]));
                    asm("v_cvt_pk_bf16_f32 %0, %1, %2" : "=v"(b0) : "v"(p[4]),  "v"(p[5]));
                    asm("v_cvt_pk_bf16_f32 %0, %1, %2" : "=v"(a1) : "v"(p[2]),  "v"(p[3]));
                    asm("v_cvt_pk_bf16_f32 %0, %1, %2" : "=v"(b1) : "v"(p[6]),  "v"(p[7]));
                    asm("v_cvt_pk_bf16_f32 %0, %1, %2" : "=v"(a2) : "v"(p[8]),  "v"(p[9]));
                    asm("v_cvt_pk_bf16_f32 %0, %1, %2" : "=v"(b2) : "v"(p[12]), "v"(p[13]));
                    asm("v_cvt_pk_bf16_f32 %0, %1, %2" : "=v"(a3) : "v"(p[10]), "v"(p[11]));
                    asm("v_cvt_pk_bf16_f32 %0, %1, %2" : "=v"(b3) : "v"(p[14]), "v"(p[15]));
                    asm volatile("v_permlane32_swap_b32 %0, %1" : "+v"(a0), "+v"(b0));
                    asm volatile("v_permlane32_swap_b32 %0, %1" : "+v"(a1), "+v"(b1));
                    asm volatile("v_permlane32_swap_b32 %0, %1" : "+v"(a2), "+v"(b2));
                    asm volatile("v_permlane32_swap_b32 %0, %1" : "+v"(a3), "+v"(b3));
                    i32x4 w0; w0[0] = (int)a0; w0[1] = (int)a1; w0[2] = (int)b0; w0[3] = (int)b1;
                    i32x4 w1; w1[0] = (int)a2; w1[1] = (int)a3; w1[2] = (int)b2; w1[3] = (int)b3;
                    pf0 = __builtin_bit_cast(s16x8, w0);
                    pf1 = __builtin_bit_cast(s16x8, w1);
                }

                // --- PV: out^T += V^T . P^T ---
                __builtin_amdgcn_s_setprio(1);
                acc[qf][0] = __builtin_amdgcn_mfma_f32_32x32x16_bf16(va00, pf0, acc[qf][0], 0, 0, 0);
                acc[qf][1] = __builtin_amdgcn_mfma_f32_32x32x16_bf16(va01, pf0, acc[qf][1], 0, 0, 0);
                acc[qf][0] = __builtin_amdgcn_mfma_f32_32x32x16_bf16(va10, pf1, acc[qf][0], 0, 0, 0);
                acc[qf][1] = __builtin_amdgcn_mfma_f32_32x32x16_bf16(va11, pf1, acc[qf][1], 0, 0, 0);
                __builtin_amdgcn_s_setprio(0);
            }
        }
        __syncthreads();
    }

    l0 += __shfl_xor(l0, 32, 64);
    l1 += __shfl_xor(l1, 32, 64);

    const float alpha = *alpha_p, beta = *beta_p;
    const float s0v = alpha / l0, s1v = alpha / l1;
#pragma unroll
    for (int qf = 0; qf < 2; qf++) {
        const float sv = qf ? s1v : s0v;
#pragma unroll
        for (int dd = 0; dd < 2; dd++) {
#pragma unroll
            for (int rg = 0; rg < 4; rg++) {
                int d0 = dd * 32 + rg * 8 + hi * 4;
                size_t idx = qbase + (size_t)qf * 32 * 768 + d0;
                f32x4 av = *reinterpret_cast<const f32x4*>(adj + idx);
                f32x4 o;
#pragma unroll
                for (int i = 0; i < 4; i++)
                    o[i] = acc[qf][dd][rg * 4 + i] * sv + beta * av[i];
                *reinterpret_cast<f32x4*>(out + idx) = o;
            }
        }
    }
}

// ---------------------------------------------------------------------------
extern "C" void kernel_launch(void* const* d_in, const int* in_sizes, int n_in,
                              void* d_out, int out_size, void* d_ws, size_t ws_size,
                              hipStream_t stream) {
    const float* v1 = (const float*)d_in[0];
    const float* v2 = (const float*)d_in[1];
    const float* Wq = (const float*)d_in[2];
    const float* bq = (const float*)d_in[3];
    const float* Wk = (const float*)d_in[4];
    const float* bk = (const float*)d_in[5];
    const float* Wv = (const float*)d_in[6];
    const float* bv = (const float*)d_in[7];
    const float* Wo = (const float*)d_in[8];
    const float* bo = (const float*)d_in[9];
    const float* alpha = (const float*)d_in[10];
    const float* beta = (const float*)d_in[11];
    float* out = (float*)d_out;

    const size_t ACT = (size_t)8192 * 768;
    const size_t WSZ = (size_t)768 * 768;
    char* ws = (char*)d_ws;
    size_t off = 0;
    auto alloc = [&](size_t bytes) {
        char* p = ws + off;
        off += (bytes + 255) & ~(size_t)255;
        return p;
    };
    unsigned short* v1b  = (unsigned short*)alloc(ACT * 2);
    unsigned short* v2b  = (unsigned short*)alloc(ACT * 2);
    unsigned short* wcat = (unsigned short*)alloc(4 * WSZ * 2);
    unsigned short* Qb   = (unsigned short*)alloc(ACT * 2);
    unsigned short* Kb   = (unsigned short*)alloc(ACT * 2);
    unsigned short* Vtb  = (unsigned short*)alloc(ACT * 2);
    float* adj = (float*)alloc(ACT * 4);

    cvt_f32_to_bf16<<<dim3(1024), dim3(256), 0, stream>>>(v1, v1b, (int)(ACT / 4));
    cvt_f32_to_bf16<<<dim3(1024), dim3(256), 0, stream>>>(v2, v2b, (int)(ACT / 4));
    cvt_weights<<<dim3((int)(4 * WSZ / 4 / 256)), dim3(256), 0, stream>>>(
        Wq, Wk, Wv, Wo, wcat, (int)(WSZ / 4));

    // 1/sqrt(768) * log2(e): folds softmax's base-2 conversion into Q.
    const float qscale = 0.03608439182435161f * 1.4426950408889634f;
    gemm_qkvo<<<dim3(1536), dim3(256), 0, stream>>>(
        v1b, v2b, wcat, bq, bk, bv, bo, Qb, Kb, Vtb, adj, qscale);

    attn_fused<<<dim3(48, 16), dim3(128), 0, stream>>>(Qb, Kb, Vtb, adj, alpha, beta, out);
}